// Round 19
// baseline (196.785 us; speedup 1.0000x reference)
//
#include <hip/hip_runtime.h>
#include <hip/hip_bf16.h>

#define BATCH 8
#define CD 512
#define NT 4096
#define EPSV 1e-5f

using u16x8 = __attribute__((ext_vector_type(8))) unsigned short;
using u16x4 = __attribute__((ext_vector_type(4))) unsigned short;
using bf8   = __attribute__((ext_vector_type(8))) short;
using f32x4 = __attribute__((ext_vector_type(4))) float;

__device__ __forceinline__ float b2f(unsigned short u) {
    union { unsigned int i; float f; } x; x.i = ((unsigned int)u) << 16; return x.f;
}
__device__ __forceinline__ unsigned short f2b(float f) {
    unsigned int x = __float_as_uint(f);
    unsigned int r = (x + 0x7fffu + ((x >> 16) & 1u)) >> 16;
    return (unsigned short)r;
}
__device__ __forceinline__ unsigned int cvtpk(float a, float b) {
    unsigned int r;
    asm("v_cvt_pk_bf16_f32 %0, %1, %2" : "=v"(r) : "v"(a), "v"(b));
    return r;
}
__device__ __forceinline__ void gload_lds16(const void* g, void* l) {
    __builtin_amdgcn_global_load_lds((const __attribute__((address_space(1))) unsigned int*)g,
                                     (__attribute__((address_space(3))) unsigned int*)l, 16, 0, 0);
}
__device__ __forceinline__ int swz8(int r) { return (r ^ (r >> 3)) & 7; }

// ---------- W fp32 -> bf16 (row-major kept) ----------
__global__ __launch_bounds__(256)
void wconv(const float* __restrict__ W0, const float* __restrict__ W1,
           const float* __restrict__ W2, const float* __restrict__ W3,
           unsigned short* __restrict__ Wb) {
    const float* src = (blockIdx.y == 0) ? W0 : (blockIdx.y == 1) ? W1 : (blockIdx.y == 2) ? W2 : W3;
    unsigned short* dst = Wb + (size_t)blockIdx.y * CD * CD;
    const int base = blockIdx.x * 4096 + threadIdx.x * 16;
    u16x8 o0, o1;
    #pragma unroll
    for (int i = 0; i < 4; ++i) {
        float4 v = *reinterpret_cast<const float4*>(src + base + i * 4);
        unsigned short* t = (i < 2) ? (unsigned short*)&o0 : (unsigned short*)&o1;
        t[(i & 1) * 4 + 0] = f2b(v.x); t[(i & 1) * 4 + 1] = f2b(v.y);
        t[(i & 1) * 4 + 2] = f2b(v.z); t[(i & 1) * 4 + 3] = f2b(v.w);
    }
    *(u16x8*)(dst + base)     = o0;
    *(u16x8*)(dst + base + 8) = o1;
}

// ---------- projection GEMM: 512-thread block = 32 tokens x FULL 512 d ----------
// 8 waves. Xs 32KB staged once. W: wave-private LDS TRIPLE-buffer (3 x 16KB),
// counted vmcnt(4) -> 3 chunks (6 loads) in flight. 80KB LDS -> 2 blocks/CU.
// Single fused 32-chunk flow (cc = d0i*16 + kc, fully unrolled, static bufs).
__global__ __launch_bounds__(512, 4)
void proj_gemm_all(const float* __restrict__ q, const float* __restrict__ k,
                   const float* __restrict__ v, const unsigned short* __restrict__ Wb,
                   unsigned short* __restrict__ Qp, unsigned short* __restrict__ Kp,
                   unsigned short* __restrict__ Vp, float* __restrict__ Kpart) {
    __shared__ __align__(16) unsigned short Xs[32 * 512];     // 32KB [tok][c] swizzled
    __shared__ __align__(16) unsigned short Wsb[3][256 * 32]; // 3 x 16KB wave-private W
    const int nper = gridDim.x >> 3;                          // 384
    const int work = (blockIdx.x & 7) * nper + (blockIdx.x >> 3);
    const int mat  = work / 1024;
    const int rem  = work - mat * 1024;
    const int b    = rem >> 7;
    const int tile = rem & 127;
    const int n0   = tile * 32;
    const float* Xb = (mat == 0 ? q : mat == 1 ? k : v) + (size_t)b * CD * NT;
    const unsigned short* W = Wb + (size_t)mat * CD * CD;
    unsigned short* Tb = (mat == 0 ? Qp : mat == 1 ? Kp : Vp) + (size_t)b * NT * CD;
    const int act = (mat < 2);

    const int tid = threadIdx.x, lane = tid & 63, wv = tid >> 6;  // wv 0..7
    const int r16 = lane & 15, g = lane >> 4;

    // ---- stage X^T tile once: 32 tok x 512 c (f32 -> bf16, transposed in regs) ----
    #pragma unroll
    for (int i = 0; i < 2; ++i) {
        const int s  = i * 512 + tid;
        const int c0 = (s >> 3) * 4;
        const int t0 = (s & 7) * 4;
        const float* p = Xb + (size_t)c0 * NT + n0 + t0;
        float4 r0 = *(const float4*)(p);
        float4 r1 = *(const float4*)(p + NT);
        float4 r2 = *(const float4*)(p + 2 * NT);
        float4 r3 = *(const float4*)(p + 3 * NT);
        float a0[4] = {r0.x, r0.y, r0.z, r0.w};
        float a1[4] = {r1.x, r1.y, r1.z, r1.w};
        float a2[4] = {r2.x, r2.y, r2.z, r2.w};
        float a3[4] = {r3.x, r3.y, r3.z, r3.w};
        #pragma unroll
        for (int j = 0; j < 4; ++j) {
            uint2 u;
            u.x = cvtpk(a0[j], a1[j]);
            u.y = cvtpk(a2[j], a3[j]);
            const int row  = t0 + j;
            const int byte = (row * 1024 + c0 * 2) ^ (swz8(row) << 4);
            *(uint2*)((char*)Xs + byte) = u;
        }
    }
    __syncthreads();   // drains vmcnt; Xs read-only, Ws wave-private from here on

    const int rl0 = lane >> 2;        // 0..15
    const int sl  = lane & 3;         // 16B slot within 64B row
    // chunk CC (0..31): d-rows [(CC>>4)*256 + wv*32, +32), cols [(CC&15)*32, +32)
    #define ISSUEW(CC) do {                                                        \
        _Pragma("unroll") for (int it_ = 0; it_ < 2; ++it_) {                      \
            const int rl_ = it_ * 16 + rl0;                                        \
            const int q_  = sl ^ ((rl_ >> 1) & 3);                                 \
            gload_lds16(W + (size_t)(((CC) >> 4) * 256 + wv * 32 + rl_) * CD + ((CC) & 15) * 32 + q_ * 8, \
                        (char*)Wsb + ((CC) % 3) * 16384 + wv * 2048 + it_ * 1024 + lane * 16); \
        }                                                                          \
    } while (0)

    #define READAF(KC) do {                                                        \
        _Pragma("unroll") for (int m_ = 0; m_ < 2; ++m_) {                         \
            const int r_ = m_ * 16 + r16;                                          \
            af[m_] = *(const bf8*)((const char*)Xs +                               \
                     ((r_ * 1024 + (KC) * 64 + g * 16) ^ (swz8(r_) << 4)));        \
        }                                                                          \
    } while (0)

    #define READBF(BUF) do {                                                       \
        const char* Wcur_ = (const char*)Wsb + (BUF) * 16384 + wv * 2048;          \
        _Pragma("unroll") for (int j_ = 0; j_ < 2; ++j_) {                         \
            const int lr_ = j_ * 16 + r16;                                         \
            bfr[j_] = *(const bf8*)(Wcur_ + lr_ * 64 + ((g ^ ((lr_ >> 1) & 3)) * 16)); \
        }                                                                          \
    } while (0)

    #define DOMFMA(ACC) do {                                                       \
        __builtin_amdgcn_s_setprio(1);                                             \
        _Pragma("unroll") for (int m_ = 0; m_ < 2; ++m_)                           \
        _Pragma("unroll") for (int j_ = 0; j_ < 2; ++j_)                           \
            ACC[m_][j_] = __builtin_amdgcn_mfma_f32_16x16x32_bf16(af[m_], bfr[j_], ACC[m_][j_], 0, 0, 0); \
        __builtin_amdgcn_s_setprio(0);                                             \
    } while (0)

    // wait: outstanding chunks = cc..min(cc+2,31); vmcnt counts 2 loads/chunk
    #define CHUNK(CC, ACC) do {                                                    \
        if ((CC) <= 29)      asm volatile("s_waitcnt vmcnt(4)" ::: "memory");      \
        else if ((CC) == 30) asm volatile("s_waitcnt vmcnt(2)" ::: "memory");      \
        else                 asm volatile("s_waitcnt vmcnt(0)" ::: "memory");      \
        __builtin_amdgcn_sched_barrier(0);                                         \
        READBF((CC) % 3);                                                          \
        READAF((CC) & 15);                                                         \
        asm volatile("s_waitcnt lgkmcnt(0)" ::: "memory");                         \
        __builtin_amdgcn_sched_barrier(0);                                         \
        if ((CC) + 3 < 32) ISSUEW((CC) + 3);                                       \
        DOMFMA(ACC);                                                               \
    } while (0)

    f32x4 accA[2][2], accB[2][2];
    #pragma unroll
    for (int m = 0; m < 2; ++m)
        #pragma unroll
        for (int j = 0; j < 2; ++j) {
            accA[m][j] = (f32x4){0.f, 0.f, 0.f, 0.f};
            accB[m][j] = (f32x4){0.f, 0.f, 0.f, 0.f};
        }

    bf8 af[2], bfr[2];
    ISSUEW(0); ISSUEW(1); ISSUEW(2);
    #pragma unroll
    for (int cc = 0; cc < 16; ++cc) CHUNK(cc, accA);
    #pragma unroll
    for (int cc = 16; cc < 32; ++cc) CHUNK(cc, accB);

    // ---- single epilogue: both 256-d halves (+ folded K-sum over the 32 tokens) ----
    float kaccA[2] = {0.f, 0.f}, kaccB[2] = {0.f, 0.f};
    #pragma unroll
    for (int m = 0; m < 2; ++m) {
        const int ib = n0 + m * 16 + (g << 2);
        #pragma unroll
        for (int j = 0; j < 2; ++j) {
            const int jbA = wv * 32 + j * 16 + r16;
            const int jbB = 256 + jbA;
            f32x4 vA = accA[m][j], vB = accB[m][j];
            #pragma unroll
            for (int r = 0; r < 4; ++r) {
                float a = vA[r], c = vB[r];
                if (act) {
                    a = (a > 0.f) ? (a + 1.f) : __expf(a);
                    c = (c > 0.f) ? (c + 1.f) : __expf(c);
                }
                if (mat == 1) { kaccA[j] += a; kaccB[j] += c; }
                Tb[(size_t)(ib + r) * CD + jbA] = f2b(a);
                Tb[(size_t)(ib + r) * CD + jbB] = f2b(c);
            }
        }
    }
    if (mat == 1) {
        #pragma unroll
        for (int j = 0; j < 2; ++j) {
            float sA = kaccA[j], sB = kaccB[j];
            sA += __shfl_xor(sA, 16, 64); sA += __shfl_xor(sA, 32, 64);
            sB += __shfl_xor(sB, 16, 64); sB += __shfl_xor(sB, 32, 64);
            if (lane < 16) {
                float* kp = Kpart + (size_t)(b * 128 + tile) * CD;
                kp[wv * 32 + j * 16 + lane]       = sA;
                kp[256 + wv * 32 + j * 16 + lane] = sB;
            }
        }
    }
    #undef ISSUEW
    #undef READAF
    #undef READBF
    #undef DOMFMA
    #undef CHUNK
}

// ---------- Ks[b][c] = sum over 128 token-tiles of Kpart ----------
__global__ __launch_bounds__(512)
void ksum_red2(const float* __restrict__ Kpart, float* __restrict__ Ks) {
    const int b = blockIdx.x, c = threadIdx.x;
    float s = 0.f;
    #pragma unroll 8
    for (int t = 0; t < 128; ++t) s += Kpart[(size_t)(b * 128 + t) * CD + c];
    Ks[b * CD + c] = s;
}

// ---------- final GEMM: out[b][d][n] = sum_c Wp[d][c]*Tm[b][n][c] + bias[d] ----------
__global__ __launch_bounds__(256)
void gemm_final(const unsigned short* __restrict__ Wp, const unsigned short* __restrict__ Tm,
                float* __restrict__ out, const float* __restrict__ bias) {
    __shared__ __align__(16) unsigned short Asm[128 * 64];
    __shared__ __align__(16) unsigned short Bsm[128 * 64];
    const int nper = gridDim.x >> 3;
    const int work = (blockIdx.x & 7) * nper + (blockIdx.x >> 3);
    const int i0 = (work & 3) * 128;
    const int j0 = ((work >> 2) & 31) * 128;
    const int b  = work >> 7;
    const unsigned short* Bb = Tm + (size_t)b * NT * CD;
    const int tid  = threadIdx.x;
    const int lane = tid & 63;
    const int wv   = tid >> 6;
    const int wi = wv >> 1, wj = wv & 1;

    f32x4 acc[4][4];
    #pragma unroll
    for (int m = 0; m < 4; ++m)
        #pragma unroll
        for (int j = 0; j < 4; ++j)
            acc[m][j] = (f32x4){0.f, 0.f, 0.f, 0.f};

    for (int k0 = 0; k0 < CD; k0 += 64) {
        #pragma unroll
        for (int it = 0; it < 4; ++it) {
            const int idx = it * 256 + tid;
            const int r = idx >> 3, p = idx & 7;
            const int ps = p ^ (r & 7);
            gload_lds16(Wp + (size_t)(i0 + r) * CD + k0 + ps * 8, (char*)Asm + idx * 16);
            gload_lds16(Bb + (size_t)(j0 + r) * CD + k0 + ps * 8, (char*)Bsm + idx * 16);
        }
        __syncthreads();
        #pragma unroll
        for (int kk = 0; kk < 2; ++kk) {
            bf8 af[4], bfr[4];
            #pragma unroll
            for (int m = 0; m < 4; ++m) {
                const int r  = wi * 64 + m * 16 + (lane & 15);
                const int kp = kk * 4 + (lane >> 4);
                af[m] = *(const bf8*)((const char*)Asm + r * 128 + ((kp ^ (r & 7)) * 16));
            }
            #pragma unroll
            for (int j = 0; j < 4; ++j) {
                const int r  = wj * 64 + j * 16 + (lane & 15);
                const int kp = kk * 4 + (lane >> 4);
                bfr[j] = *(const bf8*)((const char*)Bsm + r * 128 + ((kp ^ (r & 7)) * 16));
            }
            #pragma unroll
            for (int m = 0; m < 4; ++m)
                #pragma unroll
                for (int j = 0; j < 4; ++j)
                    acc[m][j] = __builtin_amdgcn_mfma_f32_16x16x32_bf16(af[m], bfr[j], acc[m][j], 0, 0, 0);
        }
        __syncthreads();
    }

    #pragma unroll
    for (int m = 0; m < 4; ++m) {
        const int ib = i0 + wi * 64 + m * 16 + (lane >> 4) * 4;
        #pragma unroll
        for (int j = 0; j < 4; ++j) {
            const int jb = j0 + wj * 64 + j * 16 + (lane & 15);
            f32x4 v = acc[m][j];
            #pragma unroll
            for (int r = 0; r < 4; ++r)
                out[(size_t)b * CD * NT + (size_t)(ib + r) * NT + jb] = v[r] + bias[ib + r];
        }
    }
}

// ---------- middle (MFMA, builtins only) ----------
__global__ __launch_bounds__(256)
void middle2(const unsigned short* __restrict__ Q, const unsigned short* __restrict__ K,
             const unsigned short* __restrict__ V, const float* __restrict__ Ksum,
             unsigned short* __restrict__ T) {
    __shared__ __align__(16) unsigned short sV[4][512];
    __shared__ __align__(16) unsigned short sP[4][16][32];
    const int b = blockIdx.y;
    const int tid = threadIdx.x;
    const int w = tid >> 6, lane = tid & 63;
    const int r16 = lane & 15, g = lane >> 4;
    const int n0 = blockIdx.x * 16 + w * 4;
    const unsigned short* Qb = Q + ((size_t)b * NT + n0) * CD;
    const unsigned short* Kb = K + ((size_t)b * NT + n0) * CD;
    const unsigned short* Vb = V + ((size_t)b * NT + n0) * CD;
    unsigned short* Tb = T + ((size_t)b * NT + n0) * CD;
    const int fragoff = r16 * 32 + g * 8;

    {
        const int r = lane >> 2, cq = lane & 3;
        *(u16x4*)&sP[w][r][16 + cq * 4] = (u16x4){0, 0, 0, 0};
    }

    const float* ksp = Ksum + b * CD + fragoff;
    float ks[8];
    {
        float4 a0 = *(const float4*)ksp;
        float4 a1 = *(const float4*)(ksp + 4);
        ks[0] = a0.x; ks[1] = a0.y; ks[2] = a0.z; ks[3] = a0.w;
        ks[4] = a1.x; ks[5] = a1.y; ks[6] = a1.z; ks[7] = a1.w;
    }
    unsigned short* sVw = &sV[w][0];

    for (int t = 0; t < 4; ++t) {
        asm volatile("s_waitcnt lgkmcnt(0)" ::: "memory");
        __builtin_amdgcn_sched_barrier(0);
        gload_lds16(Vb + (size_t)t * CD + lane * 8, (char*)sVw + lane * 16);

        const bf8 qf = *(const bf8*)(Qb + (size_t)t * CD + fragoff);
        const bf8 kf = *(const bf8*)(Kb + (size_t)t * CD + fragoff);

        f32x4 s = {0.f, 0.f, 0.f, 0.f};
        s = __builtin_amdgcn_mfma_f32_16x16x32_bf16(kf, qf, s, 0, 0, 0);

        float part = 0.f;
        #pragma unroll
        for (int e = 0; e < 8; ++e) part += b2f((unsigned short)qf[e]) * ks[e];
        part += __shfl_xor(part, 16, 64);
        part += __shfl_xor(part, 32, 64);
        const float z = 1.f / (part + EPSV);

        u16x4 pw;
        #pragma unroll
        for (int r = 0; r < 4; ++r) pw[r] = f2b(s[r] * z);
        *(u16x4*)&sP[w][r16][g * 4] = pw;

        asm volatile("s_waitcnt vmcnt(0) lgkmcnt(0)" ::: "memory");
        __builtin_amdgcn_sched_barrier(0);

        const bf8 pb = *(const bf8*)&sP[w][r16][g * 8];
        bf8 va0 = {}, va1 = {};
        if (g < 2) {
            #pragma unroll
            for (int e = 0; e < 8; ++e) {
                va0[e] = (short)sVw[(g * 8 + e) * 32 + r16];
                va1[e] = (short)sVw[(g * 8 + e) * 32 + 16 + r16];
            }
        }

        f32x4 o0 = {0.f, 0.f, 0.f, 0.f}, o1 = {0.f, 0.f, 0.f, 0.f};
        o0 = __builtin_amdgcn_mfma_f32_16x16x32_bf16(va0, pb, o0, 0, 0, 0);
        o1 = __builtin_amdgcn_mfma_f32_16x16x32_bf16(va1, pb, o1, 0, 0, 0);

        u16x4 w0, w1;
        #pragma unroll
        for (int r = 0; r < 4; ++r) { w0[r] = f2b(o0[r]); w1[r] = f2b(o1[r]); }
        *(u16x4*)(Tb + (size_t)t * CD + r16 * 32 + g * 4)      = w0;
        *(u16x4*)(Tb + (size_t)t * CD + r16 * 32 + 16 + g * 4) = w1;
    }
}

// ---------- launch ----------
extern "C" void kernel_launch(void* const* d_in, const int* in_sizes, int n_in,
                              void* d_out, int out_size, void* d_ws, size_t ws_size,
                              hipStream_t stream) {
    const float* q  = (const float*)d_in[0];
    const float* k  = (const float*)d_in[1];
    const float* v  = (const float*)d_in[2];
    const float* Wq = (const float*)d_in[3];
    const float* Wk = (const float*)d_in[4];
    const float* Wv = (const float*)d_in[5];
    const float* Wp = (const float*)d_in[6];
    const float* bp = (const float*)d_in[7];
    float* out = (float*)d_out;

    const size_t slab = (size_t)BATCH * NT * CD;
    unsigned short* Qp = (unsigned short*)d_ws;
    unsigned short* Kp = Qp + slab;
    unsigned short* Vp = Kp + slab;
    unsigned short* Tm = Vp + slab;
    unsigned short* Wb = Tm + slab;
    float* Kpart = (float*)(Wb + 4 * (size_t)CD * CD);
    float* Ks    = Kpart + (size_t)BATCH * 128 * CD;

    wconv<<<dim3(64, 4), 256, 0, stream>>>(Wq, Wk, Wv, Wp, Wb);

    const unsigned short* Wpb = Wb + (size_t)3 * CD * CD;

    proj_gemm_all<<<3072, 512, 0, stream>>>(q, k, v, Wb, Qp, Kp, Vp, Kpart);

    ksum_red2<<<8, 512, 0, stream>>>(Kpart, Ks);

    middle2<<<dim3(256, 8), 256, 0, stream>>>(Qp, Kp, Vp, Ks, Tm);

    gemm_final<<<1024, 256, 0, stream>>>(Wpb, Tm, out, bp);
}

// Round 20
// 174.897 us; speedup vs baseline: 1.1251x; 1.1251x over previous
//
#include <hip/hip_runtime.h>
#include <hip/hip_bf16.h>

#define BATCH 8
#define CD 512
#define NT 4096
#define EPSV 1e-5f

using u16x8 = __attribute__((ext_vector_type(8))) unsigned short;
using u16x4 = __attribute__((ext_vector_type(4))) unsigned short;
using bf8   = __attribute__((ext_vector_type(8))) short;
using f32x4 = __attribute__((ext_vector_type(4))) float;

__device__ __forceinline__ float b2f(unsigned short u) {
    union { unsigned int i; float f; } x; x.i = ((unsigned int)u) << 16; return x.f;
}
__device__ __forceinline__ unsigned short f2b(float f) {
    unsigned int x = __float_as_uint(f);
    unsigned int r = (x + 0x7fffu + ((x >> 16) & 1u)) >> 16;
    return (unsigned short)r;
}
__device__ __forceinline__ unsigned int cvtpk(float a, float b) {
    unsigned int r;
    asm("v_cvt_pk_bf16_f32 %0, %1, %2" : "=v"(r) : "v"(a), "v"(b));
    return r;
}
__device__ __forceinline__ void gload_lds16(const void* g, void* l) {
    __builtin_amdgcn_global_load_lds((const __attribute__((address_space(1))) unsigned int*)g,
                                     (__attribute__((address_space(3))) unsigned int*)l, 16, 0, 0);
}
__device__ __forceinline__ int swz8(int r) { return (r ^ (r >> 3)) & 7; }

// ---------- W fp32 -> bf16 (row-major kept) ----------
__global__ __launch_bounds__(256)
void wconv(const float* __restrict__ W0, const float* __restrict__ W1,
           const float* __restrict__ W2, const float* __restrict__ W3,
           unsigned short* __restrict__ Wb) {
    const float* src = (blockIdx.y == 0) ? W0 : (blockIdx.y == 1) ? W1 : (blockIdx.y == 2) ? W2 : W3;
    unsigned short* dst = Wb + (size_t)blockIdx.y * CD * CD;
    const int base = blockIdx.x * 4096 + threadIdx.x * 16;
    u16x8 o0, o1;
    #pragma unroll
    for (int i = 0; i < 4; ++i) {
        float4 v = *reinterpret_cast<const float4*>(src + base + i * 4);
        unsigned short* t = (i < 2) ? (unsigned short*)&o0 : (unsigned short*)&o1;
        t[(i & 1) * 4 + 0] = f2b(v.x); t[(i & 1) * 4 + 1] = f2b(v.y);
        t[(i & 1) * 4 + 2] = f2b(v.z); t[(i & 1) * 4 + 3] = f2b(v.w);
    }
    *(u16x8*)(dst + base)     = o0;
    *(u16x8*)(dst + base + 8) = o1;
}

// ---------- projection GEMM: block = 64 tokens x FULL 512 d ----------
// Xs staged ONCE (64KB, swz8 both sides). W: wave-private 8KB dbuf chunks,
// counted vmcnt(2); reg-dbuf'd X-frags (afA/afB) prefetched one chunk ahead;
// single sched_barrier per chunk; setprio(1) around MFMA cluster.
// Best-measured configuration (175.1 us total, round-16 bench).
__global__ __launch_bounds__(256)
void proj_gemm_all(const float* __restrict__ q, const float* __restrict__ k,
                   const float* __restrict__ v, const unsigned short* __restrict__ Wb,
                   unsigned short* __restrict__ Qp, unsigned short* __restrict__ Kp,
                   unsigned short* __restrict__ Vp, float* __restrict__ Kpart) {
    __shared__ __align__(16) unsigned short Xs[64 * 512];     // 64KB [tok][c] swizzled
    __shared__ __align__(16) unsigned short Wsb[2][128 * 32]; // 2 x 8KB wave-private W
    const int nper = gridDim.x >> 3;                          // 192
    const int work = (blockIdx.x & 7) * nper + (blockIdx.x >> 3);
    const int mat  = work / 512;
    const int rem  = work - mat * 512;
    const int b    = rem >> 6;
    const int tile = rem & 63;
    const int n0   = tile * 64;
    const float* Xb = (mat == 0 ? q : mat == 1 ? k : v) + (size_t)b * CD * NT;
    const unsigned short* W = Wb + (size_t)mat * CD * CD;
    unsigned short* Tb = (mat == 0 ? Qp : mat == 1 ? Kp : Vp) + (size_t)b * NT * CD;
    const int act = (mat < 2);

    const int tid = threadIdx.x, lane = tid & 63, wv = tid >> 6;
    const int r16 = lane & 15, g = lane >> 4;

    // ---- stage X^T tile once: 64 tok x 512 c (f32 -> bf16, transposed in regs) ----
    #pragma unroll 4
    for (int i = 0; i < 8; ++i) {
        const int s  = i * 256 + tid;
        const int c0 = (s >> 4) * 4;
        const int t0 = (s & 15) * 4;
        const float* p = Xb + (size_t)c0 * NT + n0 + t0;
        float4 r0 = *(const float4*)(p);
        float4 r1 = *(const float4*)(p + NT);
        float4 r2 = *(const float4*)(p + 2 * NT);
        float4 r3 = *(const float4*)(p + 3 * NT);
        float a0[4] = {r0.x, r0.y, r0.z, r0.w};
        float a1[4] = {r1.x, r1.y, r1.z, r1.w};
        float a2[4] = {r2.x, r2.y, r2.z, r2.w};
        float a3[4] = {r3.x, r3.y, r3.z, r3.w};
        #pragma unroll
        for (int j = 0; j < 4; ++j) {
            uint2 u;
            u.x = cvtpk(a0[j], a1[j]);
            u.y = cvtpk(a2[j], a3[j]);
            const int row  = t0 + j;
            const int byte = (row * 1024 + c0 * 2) ^ (swz8(row) << 4);
            *(uint2*)((char*)Xs + byte) = u;
        }
    }
    __syncthreads();   // ONLY barrier: Xs read-only, Ws wave-private from here on

    const int rl0 = lane >> 2;        // 0..15
    const int sl  = lane & 3;         // 16B slot within 64B row
    #define ISSUEW(D0I, KC, BUF) do {                                              \
        _Pragma("unroll") for (int it_ = 0; it_ < 2; ++it_) {                      \
            const int rl_ = it_ * 16 + rl0;                                        \
            const int q_  = sl ^ ((rl_ >> 1) & 3);                                 \
            gload_lds16(W + (size_t)((D0I) * 128 + wv * 32 + rl_) * CD + (KC) * 32 + q_ * 8, \
                        (char*)Wsb + (BUF) * 8192 + wv * 2048 + it_ * 1024 + lane * 16); \
        }                                                                          \
    } while (0)

    #define READAF(AF, KC) do {                                                    \
        _Pragma("unroll") for (int m_ = 0; m_ < 2; ++m_) {                         \
            const int r_ = m_ * 16 + r16;                                          \
            AF[m_] = *(const bf8*)((const char*)Xs +                               \
                     ((r_ * 1024 + (KC) * 64 + g * 16) ^ (swz8(r_) << 4)));        \
        }                                                                          \
    } while (0)

    #define READAF4(AF, KC) do {                                                   \
        _Pragma("unroll") for (int m_ = 0; m_ < 4; ++m_) {                         \
            const int r_ = m_ * 16 + r16;                                          \
            AF[m_] = *(const bf8*)((const char*)Xs +                               \
                     ((r_ * 1024 + (KC) * 64 + g * 16) ^ (swz8(r_) << 4)));        \
        }                                                                          \
    } while (0)

    #define READBF(BUF) do {                                                       \
        const char* Wcur_ = (const char*)Wsb + (BUF) * 8192 + wv * 2048;           \
        _Pragma("unroll") for (int j_ = 0; j_ < 2; ++j_) {                         \
            const int lr_ = j_ * 16 + r16;                                         \
            bfr[j_] = *(const bf8*)(Wcur_ + lr_ * 64 + ((g ^ ((lr_ >> 1) & 3)) * 16)); \
        }                                                                          \
    } while (0)

    #define DOMFMA(AF) do {                                                        \
        __builtin_amdgcn_s_setprio(1);                                             \
        _Pragma("unroll") for (int m_ = 0; m_ < 4; ++m_)                           \
        _Pragma("unroll") for (int j_ = 0; j_ < 2; ++j_)                           \
            acc[m_][j_] = __builtin_amdgcn_mfma_f32_16x16x32_bf16(AF[m_], bfr[j_], acc[m_][j_], 0, 0, 0); \
        __builtin_amdgcn_s_setprio(0);                                             \
    } while (0)

    for (int d0i = 0; d0i < 4; ++d0i) {
        f32x4 acc[4][2];
        #pragma unroll
        for (int m = 0; m < 4; ++m)
            #pragma unroll
            for (int j = 0; j < 2; ++j)
                acc[m][j] = (f32x4){0.f, 0.f, 0.f, 0.f};

        bf8 afA[4], afB[4], bfr[2];
        ISSUEW(d0i, 0, 0);
        READAF4(afA, 0);

        #pragma unroll
        for (int kp2 = 0; kp2 < 8; ++kp2) {
            const int kc = kp2 * 2;
            // ---- even chunk kc (buf0, afA) ----
            ISSUEW(d0i, kc + 1, 1);
            asm volatile("s_waitcnt vmcnt(2)" ::: "memory");
            __builtin_amdgcn_sched_barrier(0);
            READBF(0);
            READAF4(afB, kc + 1);          // independent: fills the W-wait window
            DOMFMA(afA);
            // ---- odd chunk kc+1 (buf1, afB) ----
            if (kp2 < 7) {
                ISSUEW(d0i, kc + 2, 0);
                asm volatile("s_waitcnt vmcnt(2)" ::: "memory");
            } else {
                asm volatile("s_waitcnt vmcnt(0)" ::: "memory");
            }
            __builtin_amdgcn_sched_barrier(0);
            READBF(1);
            if (kp2 < 7) READAF4(afA, kc + 2);
            DOMFMA(afB);
        }

        // epilogue for this 128-d tile (+ folded K-sum over the 64 tokens)
        float kacc[2] = {0.f, 0.f};
        #pragma unroll
        for (int m = 0; m < 4; ++m) {
            const int ib = n0 + m * 16 + (g << 2);
            #pragma unroll
            for (int j = 0; j < 2; ++j) {
                const int jb = d0i * 128 + wv * 32 + j * 16 + r16;
                f32x4 vv = acc[m][j];
                #pragma unroll
                for (int r = 0; r < 4; ++r) {
                    float val = vv[r];
                    if (act) val = (val > 0.f) ? (val + 1.f) : __expf(val);
                    if (mat == 1) kacc[j] += val;
                    Tb[(size_t)(ib + r) * CD + jb] = f2b(val);
                }
            }
        }
        if (mat == 1) {
            #pragma unroll
            for (int j = 0; j < 2; ++j) {
                float s = kacc[j];
                s += __shfl_xor(s, 16, 64);
                s += __shfl_xor(s, 32, 64);
                if (lane < 16) {
                    const int jb = d0i * 128 + wv * 32 + j * 16 + lane;
                    Kpart[(size_t)(b * 64 + tile) * CD + jb] = s;
                }
            }
        }
    }
    #undef ISSUEW
    #undef READAF
    #undef READAF4
    #undef READBF
    #undef DOMFMA
}

// ---------- Ks[b][c] = sum over 64 token-tiles of Kpart ----------
__global__ __launch_bounds__(512)
void ksum_red2(const float* __restrict__ Kpart, float* __restrict__ Ks) {
    const int b = blockIdx.x, c = threadIdx.x;
    float s = 0.f;
    #pragma unroll 8
    for (int t = 0; t < 64; ++t) s += Kpart[(size_t)(b * 64 + t) * CD + c];
    Ks[b * CD + c] = s;
}

// ---------- final GEMM: out[b][d][n] = sum_c Wp[d][c]*Tm[b][n][c] + bias[d] ----------
__global__ __launch_bounds__(256)
void gemm_final(const unsigned short* __restrict__ Wp, const unsigned short* __restrict__ Tm,
                float* __restrict__ out, const float* __restrict__ bias) {
    __shared__ __align__(16) unsigned short Asm[128 * 64];
    __shared__ __align__(16) unsigned short Bsm[128 * 64];
    const int nper = gridDim.x >> 3;
    const int work = (blockIdx.x & 7) * nper + (blockIdx.x >> 3);
    const int i0 = (work & 3) * 128;
    const int j0 = ((work >> 2) & 31) * 128;
    const int b  = work >> 7;
    const unsigned short* Bb = Tm + (size_t)b * NT * CD;
    const int tid  = threadIdx.x;
    const int lane = tid & 63;
    const int wv   = tid >> 6;
    const int wi = wv >> 1, wj = wv & 1;

    f32x4 acc[4][4];
    #pragma unroll
    for (int m = 0; m < 4; ++m)
        #pragma unroll
        for (int j = 0; j < 4; ++j)
            acc[m][j] = (f32x4){0.f, 0.f, 0.f, 0.f};

    for (int k0 = 0; k0 < CD; k0 += 64) {
        #pragma unroll
        for (int it = 0; it < 4; ++it) {
            const int idx = it * 256 + tid;
            const int r = idx >> 3, p = idx & 7;
            const int ps = p ^ (r & 7);
            gload_lds16(Wp + (size_t)(i0 + r) * CD + k0 + ps * 8, (char*)Asm + idx * 16);
            gload_lds16(Bb + (size_t)(j0 + r) * CD + k0 + ps * 8, (char*)Bsm + idx * 16);
        }
        __syncthreads();
        #pragma unroll
        for (int kk = 0; kk < 2; ++kk) {
            bf8 af[4], bfr[4];
            #pragma unroll
            for (int m = 0; m < 4; ++m) {
                const int r  = wi * 64 + m * 16 + (lane & 15);
                const int kp = kk * 4 + (lane >> 4);
                af[m] = *(const bf8*)((const char*)Asm + r * 128 + ((kp ^ (r & 7)) * 16));
            }
            #pragma unroll
            for (int j = 0; j < 4; ++j) {
                const int r  = wj * 64 + j * 16 + (lane & 15);
                const int kp = kk * 4 + (lane >> 4);
                bfr[j] = *(const bf8*)((const char*)Bsm + r * 128 + ((kp ^ (r & 7)) * 16));
            }
            #pragma unroll
            for (int m = 0; m < 4; ++m)
                #pragma unroll
                for (int j = 0; j < 4; ++j)
                    acc[m][j] = __builtin_amdgcn_mfma_f32_16x16x32_bf16(af[m], bfr[j], acc[m][j], 0, 0, 0);
        }
        __syncthreads();
    }

    #pragma unroll
    for (int m = 0; m < 4; ++m) {
        const int ib = i0 + wi * 64 + m * 16 + (lane >> 4) * 4;
        #pragma unroll
        for (int j = 0; j < 4; ++j) {
            const int jb = j0 + wj * 64 + j * 16 + (lane & 15);
            f32x4 v = acc[m][j];
            #pragma unroll
            for (int r = 0; r < 4; ++r)
                out[(size_t)b * CD * NT + (size_t)(ib + r) * NT + jb] = v[r] + bias[ib + r];
        }
    }
}

// ---------- middle (MFMA, builtins only) ----------
__global__ __launch_bounds__(256)
void middle2(const unsigned short* __restrict__ Q, const unsigned short* __restrict__ K,
             const unsigned short* __restrict__ V, const float* __restrict__ Ksum,
             unsigned short* __restrict__ T) {
    __shared__ __align__(16) unsigned short sV[4][512];
    __shared__ __align__(16) unsigned short sP[4][16][32];
    const int b = blockIdx.y;
    const int tid = threadIdx.x;
    const int w = tid >> 6, lane = tid & 63;
    const int r16 = lane & 15, g = lane >> 4;
    const int n0 = blockIdx.x * 16 + w * 4;
    const unsigned short* Qb = Q + ((size_t)b * NT + n0) * CD;
    const unsigned short* Kb = K + ((size_t)b * NT + n0) * CD;
    const unsigned short* Vb = V + ((size_t)b * NT + n0) * CD;
    unsigned short* Tb = T + ((size_t)b * NT + n0) * CD;
    const int fragoff = r16 * 32 + g * 8;

    {
        const int r = lane >> 2, cq = lane & 3;
        *(u16x4*)&sP[w][r][16 + cq * 4] = (u16x4){0, 0, 0, 0};
    }

    const float* ksp = Ksum + b * CD + fragoff;
    float ks[8];
    {
        float4 a0 = *(const float4*)ksp;
        float4 a1 = *(const float4*)(ksp + 4);
        ks[0] = a0.x; ks[1] = a0.y; ks[2] = a0.z; ks[3] = a0.w;
        ks[4] = a1.x; ks[5] = a1.y; ks[6] = a1.z; ks[7] = a1.w;
    }
    unsigned short* sVw = &sV[w][0];

    for (int t = 0; t < 4; ++t) {
        asm volatile("s_waitcnt lgkmcnt(0)" ::: "memory");
        __builtin_amdgcn_sched_barrier(0);
        gload_lds16(Vb + (size_t)t * CD + lane * 8, (char*)sVw + lane * 16);

        const bf8 qf = *(const bf8*)(Qb + (size_t)t * CD + fragoff);
        const bf8 kf = *(const bf8*)(Kb + (size_t)t * CD + fragoff);

        f32x4 s = {0.f, 0.f, 0.f, 0.f};
        s = __builtin_amdgcn_mfma_f32_16x16x32_bf16(kf, qf, s, 0, 0, 0);

        float part = 0.f;
        #pragma unroll
        for (int e = 0; e < 8; ++e) part += b2f((unsigned short)qf[e]) * ks[e];
        part += __shfl_xor(part, 16, 64);
        part += __shfl_xor(part, 32, 64);
        const float z = 1.f / (part + EPSV);

        u16x4 pw;
        #pragma unroll
        for (int r = 0; r < 4; ++r) pw[r] = f2b(s[r] * z);
        *(u16x4*)&sP[w][r16][g * 4] = pw;

        asm volatile("s_waitcnt vmcnt(0) lgkmcnt(0)" ::: "memory");
        __builtin_amdgcn_sched_barrier(0);

        const bf8 pb = *(const bf8*)&sP[w][r16][g * 8];
        bf8 va0 = {}, va1 = {};
        if (g < 2) {
            #pragma unroll
            for (int e = 0; e < 8; ++e) {
                va0[e] = (short)sVw[(g * 8 + e) * 32 + r16];
                va1[e] = (short)sVw[(g * 8 + e) * 32 + 16 + r16];
            }
        }

        f32x4 o0 = {0.f, 0.f, 0.f, 0.f}, o1 = {0.f, 0.f, 0.f, 0.f};
        o0 = __builtin_amdgcn_mfma_f32_16x16x32_bf16(va0, pb, o0, 0, 0, 0);
        o1 = __builtin_amdgcn_mfma_f32_16x16x32_bf16(va1, pb, o1, 0, 0, 0);

        u16x4 w0, w1;
        #pragma unroll
        for (int r = 0; r < 4; ++r) { w0[r] = f2b(o0[r]); w1[r] = f2b(o1[r]); }
        *(u16x4*)(Tb + (size_t)t * CD + r16 * 32 + g * 4)      = w0;
        *(u16x4*)(Tb + (size_t)t * CD + r16 * 32 + 16 + g * 4) = w1;
    }
}

// ---------- launch ----------
extern "C" void kernel_launch(void* const* d_in, const int* in_sizes, int n_in,
                              void* d_out, int out_size, void* d_ws, size_t ws_size,
                              hipStream_t stream) {
    const float* q  = (const float*)d_in[0];
    const float* k  = (const float*)d_in[1];
    const float* v  = (const float*)d_in[2];
    const float* Wq = (const float*)d_in[3];
    const float* Wk = (const float*)d_in[4];
    const float* Wv = (const float*)d_in[5];
    const float* Wp = (const float*)d_in[6];
    const float* bp = (const float*)d_in[7];
    float* out = (float*)d_out;

    const size_t slab = (size_t)BATCH * NT * CD;
    unsigned short* Qp = (unsigned short*)d_ws;
    unsigned short* Kp = Qp + slab;
    unsigned short* Vp = Kp + slab;
    unsigned short* Tm = Vp + slab;
    unsigned short* Wb = Tm + slab;
    float* Kpart = (float*)(Wb + 4 * (size_t)CD * CD);
    float* Ks    = Kpart + (size_t)512 * CD;

    wconv<<<dim3(64, 4), 256, 0, stream>>>(Wq, Wk, Wv, Wp, Wb);

    const unsigned short* Wpb = Wb + (size_t)3 * CD * CD;

    proj_gemm_all<<<1536, 256, 0, stream>>>(q, k, v, Wb, Qp, Kp, Vp, Kpart);

    ksum_red2<<<8, 512, 0, stream>>>(Kpart, Ks);

    middle2<<<dim3(256, 8), 256, 0, stream>>>(Qp, Kp, Vp, Ks, Tm);

    gemm_final<<<1024, 256, 0, stream>>>(Wpb, Tm, out, bp);
}